// Round 8
// baseline (252.559 us; speedup 1.0000x reference)
//
#include <hip/hip_runtime.h>
#include <math.h>

#define NCL 21
#define CIN 256
#define HW 4096
#define PADK 24
#define NB 2

static __device__ __forceinline__ float fastrcp(float x) {
  return __builtin_amdgcn_rcpf(x);
}

// ---------------------------------------------------------------------------
// Kernel A: f1/f2 = 1x1 conv (w @ feat + b). f1 rows are PRE-SCALED by
// 1/sqrt(21) (all three consumers -- stats, corr, norm -- multiply the dot by
// SCALE, so fold it into f1 once). Block = 16 q x 16 c-chunks; LDS reduction.
#define QT 16
#define CCH 16
__global__ __launch_bounds__(256) void k_feat(
    const float* __restrict__ feat, const float* __restrict__ w1,
    const float* __restrict__ b1, const float* __restrict__ w2,
    const float* __restrict__ b2, float* __restrict__ f1T,
    float* __restrict__ f2) {
  const int t = threadIdx.x;
  const int qi = t & 15, ch = t >> 4;  // 16 chunks of 16 channels
  const int n = blockIdx.y;
  const int q = blockIdx.x * QT + qi;
  const int c0 = ch * CCH;
  const float* fp = feat + ((size_t)n * CIN + c0) * HW + q;
  float a1[NCL], a2[NCL];
#pragma unroll
  for (int k = 0; k < NCL; ++k) { a1[k] = 0.f; a2[k] = 0.f; }
#pragma unroll
  for (int cc = 0; cc < CCH; ++cc) {
    float v = fp[(size_t)cc * HW];
#pragma unroll
    for (int k = 0; k < NCL; ++k) {  // w reads thread-uniform -> s_load
      a1[k] = fmaf(v, w1[k * CIN + c0 + cc], a1[k]);
      a2[k] = fmaf(v, w2[k * CIN + c0 + cc], a2[k]);
    }
  }
  __shared__ float p1[CCH][QT][NCL];
  __shared__ float p2[CCH][QT][NCL];
#pragma unroll
  for (int k = 0; k < NCL; ++k) { p1[ch][qi][k] = a1[k]; p2[ch][qi][k] = a2[k]; }
  __syncthreads();
  const float SCALE = 1.0f / sqrtf(21.0f);
  for (int o = t; o < QT * NCL; o += 256) {
    int qq = o & 15, k = o >> 4;
    float s1 = b1[k], s2 = b2[k];
#pragma unroll
    for (int c = 0; c < CCH; ++c) { s1 += p1[c][qq][k]; s2 += p2[c][qq][k]; }
    int qg = blockIdx.x * QT + qq;
    f1T[((size_t)n * HW + qg) * PADK + k] = s1 * SCALE;  // pre-scaled
    f2[((size_t)n * NCL + k) * HW + qg] = s2;
  }
}

// ---------------------------------------------------------------------------
// Kernel C (fused, v3): per block = (8 p-rows, n), all 4096 q in-block, then
// the k_outr epilogue for the same 8 p. R7 lesson: allocator settled at VGPR
// 132 -- 4 over the 128 cliff where waves/SIMD halve (steps at 64/128/256) --
// giving 2 rounds of 2 blocks/CU at 42% duty. Live set is only ~90 (dp[8]x
// float4 + one fg group + sums), so pin it: __launch_bounds__(256, 4) caps
// VGPR at 128 -> 4 blocks/CU -> 1024 blocks = EXACTLY one round at 4 waves/
// SIMD, zero tail (same single-round-at-cap principle as k_corr8, one band
// lower).
#define PT 8
__global__ __launch_bounds__(256, 4) void k_statsoutr(
    const float* __restrict__ f1T, const float* __restrict__ f2,
    const float* __restrict__ out, float* __restrict__ otT) {
  __shared__ float srow[PT * PADK];  // 8 rows * 24 floats = 768 B
  __shared__ float red[4][PT];
  __shared__ float linv[PT];
  const int t = threadIdx.x;
  const int n = blockIdx.y;
  const int pbase = blockIdx.x * PT;
  if (t < PT * PADK / 4) {
    ((float4*)srow)[t] =
        ((const float4*)(f1T + ((size_t)n * HW + pbase) * PADK))[t];
  }
  __syncthreads();
  const float* f2n = f2 + (size_t)n * NCL * HW;
  float sums[PT];
#pragma unroll
  for (int p = 0; p < PT; ++p) sums[p] = 0.f;
  for (int qc = 0; qc < 4; ++qc) {
    const int q0 = qc * 1024 + t * 4;
    float4 dp[PT];  // dot partials: 32 VGPR
#pragma unroll
    for (int p = 0; p < PT; ++p) dp[p] = make_float4(0.f, 0.f, 0.f, 0.f);
#pragma unroll
    for (int g = 0; g < 5; ++g) {  // k = 4g .. 4g+3
      float4 fg0 = *(const float4*)(f2n + (size_t)(4 * g + 0) * HW + q0);
      float4 fg1 = *(const float4*)(f2n + (size_t)(4 * g + 1) * HW + q0);
      float4 fg2 = *(const float4*)(f2n + (size_t)(4 * g + 2) * HW + q0);
      float4 fg3 = *(const float4*)(f2n + (size_t)(4 * g + 3) * HW + q0);
#pragma unroll
      for (int p = 0; p < PT; ++p) {
        float4 ag = *(const float4*)(srow + p * PADK + 4 * g);
        dp[p].x = fmaf(ag.x, fg0.x, dp[p].x);
        dp[p].y = fmaf(ag.x, fg0.y, dp[p].y);
        dp[p].z = fmaf(ag.x, fg0.z, dp[p].z);
        dp[p].w = fmaf(ag.x, fg0.w, dp[p].w);
        dp[p].x = fmaf(ag.y, fg1.x, dp[p].x);
        dp[p].y = fmaf(ag.y, fg1.y, dp[p].y);
        dp[p].z = fmaf(ag.y, fg1.z, dp[p].z);
        dp[p].w = fmaf(ag.y, fg1.w, dp[p].w);
        dp[p].x = fmaf(ag.z, fg2.x, dp[p].x);
        dp[p].y = fmaf(ag.z, fg2.y, dp[p].y);
        dp[p].z = fmaf(ag.z, fg2.z, dp[p].z);
        dp[p].w = fmaf(ag.z, fg2.w, dp[p].w);
        dp[p].x = fmaf(ag.w, fg3.x, dp[p].x);
        dp[p].y = fmaf(ag.w, fg3.y, dp[p].y);
        dp[p].z = fmaf(ag.w, fg3.z, dp[p].z);
        dp[p].w = fmaf(ag.w, fg3.w, dp[p].w);
      }
    }
    {  // k = 20 tail
      float4 f20 = *(const float4*)(f2n + (size_t)20 * HW + q0);
#pragma unroll
      for (int p = 0; p < PT; ++p) {
        float a20 = srow[p * PADK + 20];
        dp[p].x = fmaf(a20, f20.x, dp[p].x);
        dp[p].y = fmaf(a20, f20.y, dp[p].y);
        dp[p].z = fmaf(a20, f20.z, dp[p].z);
        dp[p].w = fmaf(a20, f20.w, dp[p].w);
      }
    }
#pragma unroll
    for (int p = 0; p < PT; ++p)
      sums[p] += __expf(dp[p].x) + __expf(dp[p].y) + __expf(dp[p].z) +
                 __expf(dp[p].w);
  }
  const int wave = t >> 6, lane = t & 63;
#pragma unroll
  for (int p = 0; p < PT; ++p) {
    float s = sums[p];
    for (int off = 32; off > 0; off >>= 1) s += __shfl_xor(s, off, 64);
    if (lane == 0) red[wave][p] = s;
  }
  __syncthreads();
  if (t < PT) {
    float tot = red[0][t] + red[1][t] + red[2][t] + red[3][t];
    linv[t] = fastrcp(tot);
  }
  __syncthreads();
  // k_outr epilogue for the 8 p of this block: 8*21 = 168 outputs.
  for (int o = t; o < PT * NCL; o += 256) {
    int pl = o & 7, c = o >> 3;
    int pg = pbase + pl;
    int i = pg >> 6, j = pg & 63;
    double sy = (double)i * (127.0 / 63.0);
    double sx = (double)j * (127.0 / 63.0);
    int y0 = (int)sy, x0 = (int)sx;
    float wy = (float)(sy - y0), wx = (float)(sx - x0);
    int y1 = min(y0 + 1, 127), x1 = min(x0 + 1, 127);
    const float* src = out + ((size_t)n * NCL + c) * (128 * 128);
    float v00 = src[y0 * 128 + x0], v10 = src[y1 * 128 + x0];
    float v01 = src[y0 * 128 + x1], v11 = src[y1 * 128 + x1];
    float r0 = v00 * (1.f - wy) + v10 * wy;
    float r1 = v01 * (1.f - wy) + v11 * wy;
    float val = r0 * (1.f - wx) + r1 * wx;
    otT[((size_t)n * HW + pg) * PADK + c] = val * linv[pl];
  }
}

// ---------------------------------------------------------------------------
// Kernel D (v8): single-round residency geometry (R7: verified, dropped out
// of top-5). fq[84]+acc[84] make VGPR<=128 impossible at Q=4, so it sits in
// the 129..256 band sized exactly to the 2 blocks/CU cap: PSPLIT=16, DPS=256,
// 4-wave blocks, grid 16x16x2 = 512 = 2 blocks/CU -> 8 waves/CU steady, no
// tail. LDS = 48 KB (2/CU = 96 KB fits). Slabs 16*672 KB = 10.8 MB.
#define PSPLIT 16
#define DPS 256
__global__ __launch_bounds__(256) void k_corr8(
    const float* __restrict__ f1T, const float* __restrict__ f2,
    const float* __restrict__ otT, float* __restrict__ part) {
  __shared__ float smem[2 * DPS * PADK];  // 48 KB: sf1 | sot
  float* sf1 = smem;
  float* sot = smem + DPS * PADK;
  const int t = threadIdx.x;  // 0..255
  const int lane = t & 63, wid = t >> 6;
  const int n = blockIdx.z, pb = blockIdx.y;
  const int pbase = pb * DPS;
  {
    const float4* gf = (const float4*)(f1T + ((size_t)n * HW + pbase) * PADK);
    const float4* go = (const float4*)(otT + ((size_t)n * HW + pbase) * PADK);
    float4* sa = (float4*)sf1;
    float4* sb = (float4*)sot;
#pragma unroll
    for (int i = 0; i < DPS * (PADK / 4) / 256; ++i) {
      sa[t + i * 256] = gf[t + i * 256];
      sb[t + i * 256] = go[t + i * 256];
    }
  }
  __syncthreads();
  const int q = blockIdx.x * 256 + lane * 4;
  const float* f2n = f2 + (size_t)n * NCL * HW;
  float4 fq[NCL];
#pragma unroll
  for (int k = 0; k < NCL; ++k)
    fq[k] = *(const float4*)(f2n + (size_t)k * HW + q);
  float4 acc[NCL];
#pragma unroll
  for (int k = 0; k < NCL; ++k) acc[k] = make_float4(0.f, 0.f, 0.f, 0.f);
  const int plo = wid * (DPS / 4);
  const int phi = plo + (DPS / 4);
#pragma unroll 2
  for (int p = plo; p < phi; ++p) {
    const float4* r1 = (const float4*)(sf1 + p * PADK);
    float a[NCL];
    *(float4*)(a + 0) = r1[0];
    *(float4*)(a + 4) = r1[1];
    *(float4*)(a + 8) = r1[2];
    *(float4*)(a + 12) = r1[3];
    *(float4*)(a + 16) = r1[4];
    a[20] = ((const float*)r1)[20];
    float d0 = 0.f, d1 = 0.f, d2 = 0.f, d3 = 0.f;  // 4 independent chains
#pragma unroll
    for (int k = 0; k < NCL; ++k) {
      d0 = fmaf(a[k], fq[k].x, d0);
      d1 = fmaf(a[k], fq[k].y, d1);
      d2 = fmaf(a[k], fq[k].z, d2);
      d3 = fmaf(a[k], fq[k].w, d3);
    }
    float w0 = __expf(d0), w1 = __expf(d1), w2 = __expf(d2), w3 = __expf(d3);
    const float4* ro = (const float4*)(sot + p * PADK);
    float o[NCL];
    *(float4*)(o + 0) = ro[0];
    *(float4*)(o + 4) = ro[1];
    *(float4*)(o + 8) = ro[2];
    *(float4*)(o + 12) = ro[3];
    *(float4*)(o + 16) = ro[4];
    o[20] = ((const float*)ro)[20];
#pragma unroll
    for (int k = 0; k < NCL; ++k) {
      acc[k].x = fmaf(o[k], w0, acc[k].x);
      acc[k].y = fmaf(o[k], w1, acc[k].y);
      acc[k].z = fmaf(o[k], w2, acc[k].z);
      acc[k].w = fmaf(o[k], w3, acc[k].w);
    }
  }
  // 3-round ping-pong combine through the (now dead) LDS tile: one wave's
  // acc = 21*64 float4 = 5.4 KB <= 48 KB buffer.
  __syncthreads();  // all ds reads of sf1/sot done; safe to reuse smem
  float4* sbuf = (float4*)smem;
  if (wid == 1) {
#pragma unroll
    for (int c = 0; c < NCL; ++c) sbuf[c * 64 + lane] = acc[c];
  }
  __syncthreads();
  if (wid == 0) {
#pragma unroll
    for (int c = 0; c < NCL; ++c) {
      float4 v = sbuf[c * 64 + lane];
      acc[c].x += v.x; acc[c].y += v.y; acc[c].z += v.z; acc[c].w += v.w;
    }
  }
  __syncthreads();
  if (wid == 3) {
#pragma unroll
    for (int c = 0; c < NCL; ++c) sbuf[c * 64 + lane] = acc[c];
  }
  __syncthreads();
  if (wid == 2) {
#pragma unroll
    for (int c = 0; c < NCL; ++c) {
      float4 v = sbuf[c * 64 + lane];
      acc[c].x += v.x; acc[c].y += v.y; acc[c].z += v.z; acc[c].w += v.w;
    }
  }
  __syncthreads();
  if (wid == 2) {
#pragma unroll
    for (int c = 0; c < NCL; ++c) sbuf[c * 64 + lane] = acc[c];
  }
  __syncthreads();
  if (wid == 0) {
    float* po = part + ((size_t)pb * NB + n) * NCL * HW + q;
#pragma unroll
    for (int c = 0; c < NCL; ++c) {
      float4 v = sbuf[c * 64 + lane];
      v.x += acc[c].x; v.y += acc[c].y; v.z += acc[c].z; v.w += acc[c].w;
      *(float4*)(po + (size_t)c * HW) = v;
    }
  }
}

// ---------------------------------------------------------------------------
// Kernel D2: corr_out[idx] = sum over the 16 partial slabs. 672 blocks,
// fully coalesced strided reads; replaces the corr_out memset too.
__global__ __launch_bounds__(256) void k_reduce(
    const float* __restrict__ part, float* __restrict__ corr_out) {
  const int idx = blockIdx.x * 256 + threadIdx.x;  // NB*NCL*HW = 672*256
  const float* p = part + idx;
  float s = 0.f;
#pragma unroll
  for (int pb = 0; pb < PSPLIT; ++pb)
    s += p[(size_t)pb * (NB * NCL * HW)];
  corr_out[idx] = s;
}

// ---------------------------------------------------------------------------
// Kernel E (fused): per sampled row (i, n): compute the unnormalized exp-row
// straight into LDS (min/max normalization is invariant to the softmax
// denominator), bilinear tables in-block, upsample 64->128, min/max
// normalize, write >0.5 booleans as 1.0/0.0.
__global__ __launch_bounds__(256) void k_norm(
    const float* __restrict__ f1T, const float* __restrict__ f2,
    const int* __restrict__ index, float* __restrict__ out0) {
  __shared__ float row[HW];
  __shared__ float redmn[4], redmx[4];
  __shared__ float wt[128];
  __shared__ int it[128];
  const int t = threadIdx.x;
  const int i = blockIdx.x;
  const int n = blockIdx.y;
  if (t < 128) {
    double s = (double)t * (63.0 / 127.0);
    int i0 = (int)s;
    wt[t] = (float)(s - i0);
    it[t] = i0;
  }
  int p = index[i];
  p = max(0, min(p, HW - 1));
  const float* f1p = f1T + ((size_t)n * HW + p) * PADK;
  float a[NCL];
#pragma unroll
  for (int k = 0; k < NCL; ++k) a[k] = f1p[k];
  const float* f2n = f2 + (size_t)n * NCL * HW;
  for (int qc = 0; qc < 4; ++qc) {
    const int q0 = qc * 1024 + t * 4;
    float d0 = 0.f, d1 = 0.f, d2 = 0.f, d3 = 0.f;
#pragma unroll
    for (int k = 0; k < NCL; ++k) {
      float4 f = *(const float4*)(f2n + (size_t)k * HW + q0);
      d0 = fmaf(a[k], f.x, d0);
      d1 = fmaf(a[k], f.y, d1);
      d2 = fmaf(a[k], f.z, d2);
      d3 = fmaf(a[k], f.w, d3);
    }
    *(float4*)(row + q0) =
        make_float4(__expf(d0), __expf(d1), __expf(d2), __expf(d3));
  }
  __syncthreads();
  float vv[64];
  float lmn = 1e30f, lmx = -1e30f;
  for (int j = 0; j < 64; ++j) {
    int pix = t + j * 256;
    int yy = pix >> 7, xx = pix & 127;
    int y0 = it[yy], x0 = it[xx];
    float wy = wt[yy], wx = wt[xx];
    int y1 = min(y0 + 1, 63), x1 = min(x0 + 1, 63);
    float r0 = row[y0 * 64 + x0] * (1.f - wy) + row[y1 * 64 + x0] * wy;
    float r1 = row[y0 * 64 + x1] * (1.f - wy) + row[y1 * 64 + x1] * wy;
    float v = r0 * (1.f - wx) + r1 * wx;
    vv[j] = v;
    lmn = fminf(lmn, v);
    lmx = fmaxf(lmx, v);
  }
  for (int off = 32; off > 0; off >>= 1) {
    lmn = fminf(lmn, __shfl_xor(lmn, off, 64));
    lmx = fmaxf(lmx, __shfl_xor(lmx, off, 64));
  }
  const int wave = t >> 6, lane = t & 63;
  if (lane == 0) { redmn[wave] = lmn; redmx[wave] = lmx; }
  __syncthreads();
  float mn = fminf(fminf(redmn[0], redmn[1]), fminf(redmn[2], redmn[3]));
  float mx = fmaxf(fmaxf(redmx[0], redmx[1]), fmaxf(redmx[2], redmx[3]));
  float rng = mx - mn;
  float* slot = out0 + ((size_t)n * 128 + i) * (128 * 128);
  for (int j = 0; j < 64; ++j) {
    int pix = t + j * 256;
    float nrm = (vv[j] - mn) / rng;
    slot[pix] = (nrm > 0.5f) ? 1.0f : 0.0f;
  }
}

// ---------------------------------------------------------------------------
extern "C" void kernel_launch(void* const* d_in, const int* in_sizes, int n_in,
                              void* d_out, int out_size, void* d_ws,
                              size_t ws_size, hipStream_t stream) {
  (void)in_sizes; (void)n_in; (void)out_size; (void)ws_size;
  const float* feat = (const float*)d_in[0];
  const float* out  = (const float*)d_in[1];
  const float* w1   = (const float*)d_in[2];
  const float* b1   = (const float*)d_in[3];
  const float* w2   = (const float*)d_in[4];
  const float* b2   = (const float*)d_in[5];
  const int* index  = (const int*)d_in[6];

  float* ws   = (float*)d_ws;
  float* f1T  = ws;                                   // 2*4096*24 = 196608
  float* f2   = ws + 196608;                          // 2*21*4096 = 172032
  float* otT  = ws + 196608 + 172032;                 // 196608

  float* out0     = (float*)d_out;                    // 2*128*128*128
  float* corr_out = out0 + (size_t)NB * 128 * 128 * 128;  // 2*21*4096
  // partial slabs: 16 * 2 * 21 * 4096 floats = 10.8 MB, parked inside the
  // out0 region (16.8 MB) -- consumed by k_reduce before k_norm writes out0.
  float* part = out0;

  k_feat<<<dim3(HW / QT, 2), 256, 0, stream>>>(feat, w1, b1, w2, b2, f1T, f2);
  k_statsoutr<<<dim3(HW / PT, 2), 256, 0, stream>>>(f1T, f2, out, otT);
  k_corr8<<<dim3(16, PSPLIT, 2), 256, 0, stream>>>(f1T, f2, otT, part);
  k_reduce<<<dim3(672), 256, 0, stream>>>(part, corr_out);
  k_norm<<<dim3(128, 2), 256, 0, stream>>>(f1T, f2, index, out0);
}

// Round 9
// 178.172 us; speedup vs baseline: 1.4175x; 1.4175x over previous
//
#include <hip/hip_runtime.h>
#include <math.h>

#define NCL 21
#define CIN 256
#define HW 4096
#define PADK 24
#define NB 2

static __device__ __forceinline__ float fastrcp(float x) {
  return __builtin_amdgcn_rcpf(x);
}

// ---------------------------------------------------------------------------
// Kernel A: f1/f2 = 1x1 conv (w @ feat + b). f1 rows are PRE-SCALED by
// 1/sqrt(21) (all three consumers -- stats, corr, norm -- multiply the dot by
// SCALE, so fold it into f1 once). Block = 16 q x 16 c-chunks; LDS reduction.
#define QT 16
#define CCH 16
__global__ __launch_bounds__(256) void k_feat(
    const float* __restrict__ feat, const float* __restrict__ w1,
    const float* __restrict__ b1, const float* __restrict__ w2,
    const float* __restrict__ b2, float* __restrict__ f1T,
    float* __restrict__ f2) {
  const int t = threadIdx.x;
  const int qi = t & 15, ch = t >> 4;  // 16 chunks of 16 channels
  const int n = blockIdx.y;
  const int q = blockIdx.x * QT + qi;
  const int c0 = ch * CCH;
  const float* fp = feat + ((size_t)n * CIN + c0) * HW + q;
  float a1[NCL], a2[NCL];
#pragma unroll
  for (int k = 0; k < NCL; ++k) { a1[k] = 0.f; a2[k] = 0.f; }
#pragma unroll
  for (int cc = 0; cc < CCH; ++cc) {
    float v = fp[(size_t)cc * HW];
#pragma unroll
    for (int k = 0; k < NCL; ++k) {  // w reads thread-uniform -> s_load
      a1[k] = fmaf(v, w1[k * CIN + c0 + cc], a1[k]);
      a2[k] = fmaf(v, w2[k * CIN + c0 + cc], a2[k]);
    }
  }
  __shared__ float p1[CCH][QT][NCL];
  __shared__ float p2[CCH][QT][NCL];
#pragma unroll
  for (int k = 0; k < NCL; ++k) { p1[ch][qi][k] = a1[k]; p2[ch][qi][k] = a2[k]; }
  __syncthreads();
  const float SCALE = 1.0f / sqrtf(21.0f);
  for (int o = t; o < QT * NCL; o += 256) {
    int qq = o & 15, k = o >> 4;
    float s1 = b1[k], s2 = b2[k];
#pragma unroll
    for (int c = 0; c < CCH; ++c) { s1 += p1[c][qq][k]; s2 += p2[c][qq][k]; }
    int qg = blockIdx.x * QT + qq;
    f1T[((size_t)n * HW + qg) * PADK + k] = s1 * SCALE;  // pre-scaled
    f2[((size_t)n * NCL + k) * HW + qg] = s2;
  }
}

// ---------------------------------------------------------------------------
// Kernel C (fused, v4): per block = (8 p-rows, n), all 4096 q in-block, then
// the k_outr epilogue for the same 8 p. R8 lesson: __launch_bounds__(256,4)
// made the allocator spill to scratch (VGPR 64, 252 MB FETCH, 115 us) -- the
// q=4 live set (dp[8]xfloat4=32 + 4 float4 loads in flight) can't fit 128.
// Cut registers STRUCTURALLY instead: q=2 per thread (float2). dp 32->16,
// in-flight fg 16->8 -> expected VGPR ~100 -> 4-5 waves/SIMD, 1024 blocks
// ~= one residency round. qc iterations double (srow broadcast ds ~384/wave
// ~= 20 us/CU at the ~8cyc/broadcast-b128 rate calibrated on R3); f2 L2
// traffic and FMA count unchanged.
#define PT 8
__global__ __launch_bounds__(256) void k_statsoutr(
    const float* __restrict__ f1T, const float* __restrict__ f2,
    const float* __restrict__ out, float* __restrict__ otT) {
  __shared__ float srow[PT * PADK];  // 8 rows * 24 floats = 768 B
  __shared__ float red[4][PT];
  __shared__ float linv[PT];
  const int t = threadIdx.x;
  const int n = blockIdx.y;
  const int pbase = blockIdx.x * PT;
  if (t < PT * PADK / 4) {
    ((float4*)srow)[t] =
        ((const float4*)(f1T + ((size_t)n * HW + pbase) * PADK))[t];
  }
  __syncthreads();
  const float* f2n = f2 + (size_t)n * NCL * HW;
  float sums[PT];
#pragma unroll
  for (int p = 0; p < PT; ++p) sums[p] = 0.f;
  for (int qc = 0; qc < 8; ++qc) {
    const int q0 = qc * 512 + t * 2;
    float2 dp[PT];  // dot partials: 16 VGPR
#pragma unroll
    for (int p = 0; p < PT; ++p) dp[p] = make_float2(0.f, 0.f);
#pragma unroll
    for (int g = 0; g < 5; ++g) {  // k = 4g .. 4g+3
      float2 fg0 = *(const float2*)(f2n + (size_t)(4 * g + 0) * HW + q0);
      float2 fg1 = *(const float2*)(f2n + (size_t)(4 * g + 1) * HW + q0);
      float2 fg2 = *(const float2*)(f2n + (size_t)(4 * g + 2) * HW + q0);
      float2 fg3 = *(const float2*)(f2n + (size_t)(4 * g + 3) * HW + q0);
#pragma unroll
      for (int p = 0; p < PT; ++p) {
        float4 ag = *(const float4*)(srow + p * PADK + 4 * g);
        dp[p].x = fmaf(ag.x, fg0.x, dp[p].x);
        dp[p].y = fmaf(ag.x, fg0.y, dp[p].y);
        dp[p].x = fmaf(ag.y, fg1.x, dp[p].x);
        dp[p].y = fmaf(ag.y, fg1.y, dp[p].y);
        dp[p].x = fmaf(ag.z, fg2.x, dp[p].x);
        dp[p].y = fmaf(ag.z, fg2.y, dp[p].y);
        dp[p].x = fmaf(ag.w, fg3.x, dp[p].x);
        dp[p].y = fmaf(ag.w, fg3.y, dp[p].y);
      }
    }
    {  // k = 20 tail
      float2 f20 = *(const float2*)(f2n + (size_t)20 * HW + q0);
#pragma unroll
      for (int p = 0; p < PT; ++p) {
        float a20 = srow[p * PADK + 20];
        dp[p].x = fmaf(a20, f20.x, dp[p].x);
        dp[p].y = fmaf(a20, f20.y, dp[p].y);
      }
    }
#pragma unroll
    for (int p = 0; p < PT; ++p)
      sums[p] += __expf(dp[p].x) + __expf(dp[p].y);
  }
  const int wave = t >> 6, lane = t & 63;
#pragma unroll
  for (int p = 0; p < PT; ++p) {
    float s = sums[p];
    for (int off = 32; off > 0; off >>= 1) s += __shfl_xor(s, off, 64);
    if (lane == 0) red[wave][p] = s;
  }
  __syncthreads();
  if (t < PT) {
    float tot = red[0][t] + red[1][t] + red[2][t] + red[3][t];
    linv[t] = fastrcp(tot);
  }
  __syncthreads();
  // k_outr epilogue for the 8 p of this block: 8*21 = 168 outputs.
  for (int o = t; o < PT * NCL; o += 256) {
    int pl = o & 7, c = o >> 3;
    int pg = pbase + pl;
    int i = pg >> 6, j = pg & 63;
    double sy = (double)i * (127.0 / 63.0);
    double sx = (double)j * (127.0 / 63.0);
    int y0 = (int)sy, x0 = (int)sx;
    float wy = (float)(sy - y0), wx = (float)(sx - x0);
    int y1 = min(y0 + 1, 127), x1 = min(x0 + 1, 127);
    const float* src = out + ((size_t)n * NCL + c) * (128 * 128);
    float v00 = src[y0 * 128 + x0], v10 = src[y1 * 128 + x0];
    float v01 = src[y0 * 128 + x1], v11 = src[y1 * 128 + x1];
    float r0 = v00 * (1.f - wy) + v10 * wy;
    float r1 = v01 * (1.f - wy) + v11 * wy;
    float val = r0 * (1.f - wx) + r1 * wx;
    otT[((size_t)n * HW + pg) * PADK + c] = val * linv[pl];
  }
}

// ---------------------------------------------------------------------------
// Kernel D (v8): single-round residency geometry (R7: verified, dropped out
// of top-5). fq[84]+acc[84] make VGPR<=128 impossible at Q=4, so it sits in
// the 129..256 band sized exactly to the 2 blocks/CU cap: PSPLIT=16, DPS=256,
// 4-wave blocks, grid 16x16x2 = 512 = 2 blocks/CU -> 8 waves/CU steady, no
// tail. LDS = 48 KB (2/CU = 96 KB fits). Slabs 16*672 KB = 10.8 MB.
#define PSPLIT 16
#define DPS 256
__global__ __launch_bounds__(256) void k_corr8(
    const float* __restrict__ f1T, const float* __restrict__ f2,
    const float* __restrict__ otT, float* __restrict__ part) {
  __shared__ float smem[2 * DPS * PADK];  // 48 KB: sf1 | sot
  float* sf1 = smem;
  float* sot = smem + DPS * PADK;
  const int t = threadIdx.x;  // 0..255
  const int lane = t & 63, wid = t >> 6;
  const int n = blockIdx.z, pb = blockIdx.y;
  const int pbase = pb * DPS;
  {
    const float4* gf = (const float4*)(f1T + ((size_t)n * HW + pbase) * PADK);
    const float4* go = (const float4*)(otT + ((size_t)n * HW + pbase) * PADK);
    float4* sa = (float4*)sf1;
    float4* sb = (float4*)sot;
#pragma unroll
    for (int i = 0; i < DPS * (PADK / 4) / 256; ++i) {
      sa[t + i * 256] = gf[t + i * 256];
      sb[t + i * 256] = go[t + i * 256];
    }
  }
  __syncthreads();
  const int q = blockIdx.x * 256 + lane * 4;
  const float* f2n = f2 + (size_t)n * NCL * HW;
  float4 fq[NCL];
#pragma unroll
  for (int k = 0; k < NCL; ++k)
    fq[k] = *(const float4*)(f2n + (size_t)k * HW + q);
  float4 acc[NCL];
#pragma unroll
  for (int k = 0; k < NCL; ++k) acc[k] = make_float4(0.f, 0.f, 0.f, 0.f);
  const int plo = wid * (DPS / 4);
  const int phi = plo + (DPS / 4);
#pragma unroll 2
  for (int p = plo; p < phi; ++p) {
    const float4* r1 = (const float4*)(sf1 + p * PADK);
    float a[NCL];
    *(float4*)(a + 0) = r1[0];
    *(float4*)(a + 4) = r1[1];
    *(float4*)(a + 8) = r1[2];
    *(float4*)(a + 12) = r1[3];
    *(float4*)(a + 16) = r1[4];
    a[20] = ((const float*)r1)[20];
    float d0 = 0.f, d1 = 0.f, d2 = 0.f, d3 = 0.f;  // 4 independent chains
#pragma unroll
    for (int k = 0; k < NCL; ++k) {
      d0 = fmaf(a[k], fq[k].x, d0);
      d1 = fmaf(a[k], fq[k].y, d1);
      d2 = fmaf(a[k], fq[k].z, d2);
      d3 = fmaf(a[k], fq[k].w, d3);
    }
    float w0 = __expf(d0), w1 = __expf(d1), w2 = __expf(d2), w3 = __expf(d3);
    const float4* ro = (const float4*)(sot + p * PADK);
    float o[NCL];
    *(float4*)(o + 0) = ro[0];
    *(float4*)(o + 4) = ro[1];
    *(float4*)(o + 8) = ro[2];
    *(float4*)(o + 12) = ro[3];
    *(float4*)(o + 16) = ro[4];
    o[20] = ((const float*)ro)[20];
#pragma unroll
    for (int k = 0; k < NCL; ++k) {
      acc[k].x = fmaf(o[k], w0, acc[k].x);
      acc[k].y = fmaf(o[k], w1, acc[k].y);
      acc[k].z = fmaf(o[k], w2, acc[k].z);
      acc[k].w = fmaf(o[k], w3, acc[k].w);
    }
  }
  // 3-round ping-pong combine through the (now dead) LDS tile: one wave's
  // acc = 21*64 float4 = 5.4 KB <= 48 KB buffer.
  __syncthreads();  // all ds reads of sf1/sot done; safe to reuse smem
  float4* sbuf = (float4*)smem;
  if (wid == 1) {
#pragma unroll
    for (int c = 0; c < NCL; ++c) sbuf[c * 64 + lane] = acc[c];
  }
  __syncthreads();
  if (wid == 0) {
#pragma unroll
    for (int c = 0; c < NCL; ++c) {
      float4 v = sbuf[c * 64 + lane];
      acc[c].x += v.x; acc[c].y += v.y; acc[c].z += v.z; acc[c].w += v.w;
    }
  }
  __syncthreads();
  if (wid == 3) {
#pragma unroll
    for (int c = 0; c < NCL; ++c) sbuf[c * 64 + lane] = acc[c];
  }
  __syncthreads();
  if (wid == 2) {
#pragma unroll
    for (int c = 0; c < NCL; ++c) {
      float4 v = sbuf[c * 64 + lane];
      acc[c].x += v.x; acc[c].y += v.y; acc[c].z += v.z; acc[c].w += v.w;
    }
  }
  __syncthreads();
  if (wid == 2) {
#pragma unroll
    for (int c = 0; c < NCL; ++c) sbuf[c * 64 + lane] = acc[c];
  }
  __syncthreads();
  if (wid == 0) {
    float* po = part + ((size_t)pb * NB + n) * NCL * HW + q;
#pragma unroll
    for (int c = 0; c < NCL; ++c) {
      float4 v = sbuf[c * 64 + lane];
      v.x += acc[c].x; v.y += acc[c].y; v.z += acc[c].z; v.w += acc[c].w;
      *(float4*)(po + (size_t)c * HW) = v;
    }
  }
}

// ---------------------------------------------------------------------------
// Kernel D2: corr_out[idx] = sum over the 16 partial slabs. 672 blocks,
// fully coalesced strided reads; replaces the corr_out memset too.
__global__ __launch_bounds__(256) void k_reduce(
    const float* __restrict__ part, float* __restrict__ corr_out) {
  const int idx = blockIdx.x * 256 + threadIdx.x;  // NB*NCL*HW = 672*256
  const float* p = part + idx;
  float s = 0.f;
#pragma unroll
  for (int pb = 0; pb < PSPLIT; ++pb)
    s += p[(size_t)pb * (NB * NCL * HW)];
  corr_out[idx] = s;
}

// ---------------------------------------------------------------------------
// Kernel E (fused): per sampled row (i, n): compute the unnormalized exp-row
// straight into LDS (min/max normalization is invariant to the softmax
// denominator), bilinear tables in-block, upsample 64->128, min/max
// normalize, write >0.5 booleans as 1.0/0.0.
__global__ __launch_bounds__(256) void k_norm(
    const float* __restrict__ f1T, const float* __restrict__ f2,
    const int* __restrict__ index, float* __restrict__ out0) {
  __shared__ float row[HW];
  __shared__ float redmn[4], redmx[4];
  __shared__ float wt[128];
  __shared__ int it[128];
  const int t = threadIdx.x;
  const int i = blockIdx.x;
  const int n = blockIdx.y;
  if (t < 128) {
    double s = (double)t * (63.0 / 127.0);
    int i0 = (int)s;
    wt[t] = (float)(s - i0);
    it[t] = i0;
  }
  int p = index[i];
  p = max(0, min(p, HW - 1));
  const float* f1p = f1T + ((size_t)n * HW + p) * PADK;
  float a[NCL];
#pragma unroll
  for (int k = 0; k < NCL; ++k) a[k] = f1p[k];
  const float* f2n = f2 + (size_t)n * NCL * HW;
  for (int qc = 0; qc < 4; ++qc) {
    const int q0 = qc * 1024 + t * 4;
    float d0 = 0.f, d1 = 0.f, d2 = 0.f, d3 = 0.f;
#pragma unroll
    for (int k = 0; k < NCL; ++k) {
      float4 f = *(const float4*)(f2n + (size_t)k * HW + q0);
      d0 = fmaf(a[k], f.x, d0);
      d1 = fmaf(a[k], f.y, d1);
      d2 = fmaf(a[k], f.z, d2);
      d3 = fmaf(a[k], f.w, d3);
    }
    *(float4*)(row + q0) =
        make_float4(__expf(d0), __expf(d1), __expf(d2), __expf(d3));
  }
  __syncthreads();
  float vv[64];
  float lmn = 1e30f, lmx = -1e30f;
  for (int j = 0; j < 64; ++j) {
    int pix = t + j * 256;
    int yy = pix >> 7, xx = pix & 127;
    int y0 = it[yy], x0 = it[xx];
    float wy = wt[yy], wx = wt[xx];
    int y1 = min(y0 + 1, 63), x1 = min(x0 + 1, 63);
    float r0 = row[y0 * 64 + x0] * (1.f - wy) + row[y1 * 64 + x0] * wy;
    float r1 = row[y0 * 64 + x1] * (1.f - wy) + row[y1 * 64 + x1] * wy;
    float v = r0 * (1.f - wx) + r1 * wx;
    vv[j] = v;
    lmn = fminf(lmn, v);
    lmx = fmaxf(lmx, v);
  }
  for (int off = 32; off > 0; off >>= 1) {
    lmn = fminf(lmn, __shfl_xor(lmn, off, 64));
    lmx = fmaxf(lmx, __shfl_xor(lmx, off, 64));
  }
  const int wave = t >> 6, lane = t & 63;
  if (lane == 0) { redmn[wave] = lmn; redmx[wave] = lmx; }
  __syncthreads();
  float mn = fminf(fminf(redmn[0], redmn[1]), fminf(redmn[2], redmn[3]));
  float mx = fmaxf(fmaxf(redmx[0], redmx[1]), fmaxf(redmx[2], redmx[3]));
  float rng = mx - mn;
  float* slot = out0 + ((size_t)n * 128 + i) * (128 * 128);
  for (int j = 0; j < 64; ++j) {
    int pix = t + j * 256;
    float nrm = (vv[j] - mn) / rng;
    slot[pix] = (nrm > 0.5f) ? 1.0f : 0.0f;
  }
}

// ---------------------------------------------------------------------------
extern "C" void kernel_launch(void* const* d_in, const int* in_sizes, int n_in,
                              void* d_out, int out_size, void* d_ws,
                              size_t ws_size, hipStream_t stream) {
  (void)in_sizes; (void)n_in; (void)out_size; (void)ws_size;
  const float* feat = (const float*)d_in[0];
  const float* out  = (const float*)d_in[1];
  const float* w1   = (const float*)d_in[2];
  const float* b1   = (const float*)d_in[3];
  const float* w2   = (const float*)d_in[4];
  const float* b2   = (const float*)d_in[5];
  const int* index  = (const int*)d_in[6];

  float* ws   = (float*)d_ws;
  float* f1T  = ws;                                   // 2*4096*24 = 196608
  float* f2   = ws + 196608;                          // 2*21*4096 = 172032
  float* otT  = ws + 196608 + 172032;                 // 196608

  float* out0     = (float*)d_out;                    // 2*128*128*128
  float* corr_out = out0 + (size_t)NB * 128 * 128 * 128;  // 2*21*4096
  // partial slabs: 16 * 2 * 21 * 4096 floats = 10.8 MB, parked inside the
  // out0 region (16.8 MB) -- consumed by k_reduce before k_norm writes out0.
  float* part = out0;

  k_feat<<<dim3(HW / QT, 2), 256, 0, stream>>>(feat, w1, b1, w2, b2, f1T, f2);
  k_statsoutr<<<dim3(HW / PT, 2), 256, 0, stream>>>(f1T, f2, out, otT);
  k_corr8<<<dim3(16, PSPLIT, 2), 256, 0, stream>>>(f1T, f2, otT, part);
  k_reduce<<<dim3(672), 256, 0, stream>>>(part, corr_out);
  k_norm<<<dim3(128, 2), 256, 0, stream>>>(f1T, f2, index, out0);
}